// Round 1
// baseline (504.169 us; speedup 1.0000x reference)
//
#include <hip/hip_runtime.h>

#define Mdim 64
#define Ndim 64
#define SP 65            // padded row stride (bank-conflict-free both directions)
#define NT 256
#define PER_T 32         // 8192 nodes / 256 threads
#define ITERS 48
#define A_SZ (Mdim*SP)

__device__ __forceinline__ float wave_reduce(float v) {
    #pragma unroll
    for (int off = 32; off > 0; off >>= 1) v += __shfl_down(v, off, 64);
    return v;
}

__device__ __forceinline__ float block_reduce(float v, float* red) {
    v = wave_reduce(v);
    int wid = threadIdx.x >> 6, lane = threadIdx.x & 63;
    if (lane == 0) red[wid] = v;
    __syncthreads();
    float s = red[0] + red[1] + red[2] + red[3];
    __syncthreads();
    return s;
}

// One workgroup per unit-input RHS i0. Solves the SPD symmetrized crossbar
// system with PCG, preconditioned by exact per-line tridiagonal solves.
extern "C" __global__ __launch_bounds__(NT)
void solve_k(const float* __restrict__ W, float* __restrict__ Kout) {
    extern __shared__ float lds[];
    float* G    = lds;                 // [64][65]  G[i][j] = W[j][i]*1e-3
    float* invA = G    + A_SZ;         // [64][65]  row-line Thomas inverses
    float* invB = invA + A_SZ;         // [64][65]  col-line Thomas inverses (line-major)
    float* pb   = invB + A_SZ;         // [2][64][65] search direction
    float* zb   = pb   + 2*A_SZ;       // [2][64][65] precond residual / scratch
    float* red  = zb   + 2*A_SZ;       // [8] reduction scratch

    const int t = threadIdx.x;
    const float gl = 0.5f, gin = 0.5f, gout = 0.5f, cmap = 1e-3f;

    // ---- load conductances ----
    for (int s = t; s < Mdim*Ndim; s += NT) {
        int i = s >> 6, j = s & 63;
        G[i*SP + j] = W[j*Mdim + i] * cmap;
    }
    __syncthreads();

    // ---- factor the 128 tridiagonal lines (constant off-diag = -gl) ----
    if (t < 64) {                       // word line i = t (varies over j)
        int i = t; float prev = 0.f;
        #pragma unroll 1
        for (int k = 0; k < 64; ++k) {
            float b = G[i*SP + k] + gl*((k > 0) + (k < 63)) + (k == 0 ? gin : 0.f);
            float inv = 1.f / (b - gl*gl*prev);
            invA[i*SP + k] = inv; prev = inv;
        }
    } else if (t < 128) {               // bit line j = t-64 (varies over i)
        int j = t - 64; float prev = 0.f;
        #pragma unroll 1
        for (int k = 0; k < 64; ++k) {
            float b = G[k*SP + j] + gl*((k > 0) + (k < 63)) + (k == 63 ? gout : 0.f);
            float inv = 1.f / (b - gl*gl*prev);
            invB[j*SP + k] = inv; prev = inv;
        }
    }
    __syncthreads();

    // ---- per-thread node ownership: 32 consecutive nodes (half a row) ----
    const int half = (t >= 128);            // 0 = word-line nodes, 1 = bit-line nodes
    const int tl   = t & 127;
    const int row  = tl >> 1;
    const int jb   = (tl & 1) * 32;
    const int base = half*A_SZ + row*SP + jb;

    float x[PER_T], r[PER_T];
    #pragma unroll
    for (int s = 0; s < PER_T; ++s) { x[s] = 0.f; r[s] = 0.f; }
    const int i0 = blockIdx.x;
    if (half == 0 && row == i0 && jb == 0) r[0] = gin;   // RHS: g_in at node (i0, j=0)
    float rz = 0.f;

    #pragma unroll 1
    for (int it = 0; it < ITERS; ++it) {
        // ---- z = M^{-1} r ----
        #pragma unroll
        for (int s = 0; s < PER_T; ++s) zb[base + s] = r[s];
        __syncthreads();
        if (t < 64) {                   // row solves (wave 0)
            int i = t;
            float* L = zb + i*SP; const float* IV = invA + i*SP;
            float prev = L[0]*IV[0]; L[0] = prev;
            #pragma unroll
            for (int k = 1; k < 64; ++k) { prev = (L[k] + gl*prev)*IV[k]; L[k] = prev; }
            #pragma unroll
            for (int k = 62; k >= 0; --k) { prev = L[k] + gl*IV[k]*prev; L[k] = prev; }
        } else if (t < 128) {           // column solves (wave 1), strided but conflict-free
            int j = t - 64;
            float* L = zb + A_SZ + j; const float* IV = invB + j*SP;
            float prev = L[0]*IV[0]; L[0] = prev;
            #pragma unroll
            for (int k = 1; k < 64; ++k) { prev = (L[k*SP] + gl*prev)*IV[k]; L[k*SP] = prev; }
            #pragma unroll
            for (int k = 62; k >= 0; --k) { prev = L[k*SP] + gl*IV[k]*prev; L[k*SP] = prev; }
        }
        __syncthreads();

        // ---- rz_new = r.z ; p = z + beta p ----
        float loc = 0.f;
        #pragma unroll
        for (int s = 0; s < PER_T; ++s) loc += r[s]*zb[base + s];
        float rz_new = block_reduce(loc, red);
        if (it == 0) {
            #pragma unroll
            for (int s = 0; s < PER_T; ++s) pb[base + s] = zb[base + s];
        } else {
            float beta = (rz > 0.f) ? rz_new/rz : 0.f;
            #pragma unroll
            for (int s = 0; s < PER_T; ++s) pb[base + s] = zb[base + s] + beta*pb[base + s];
        }
        rz = rz_new;
        __syncthreads();

        // ---- q = S p ; pq = p.q ----
        float q[PER_T]; float pq = 0.f;
        if (half == 0) {
            #pragma unroll
            for (int s = 0; s < PER_T; ++s) {
                int j = jb + s;
                float pc = pb[base + s];
                float g  = G[row*SP + j];
                float diag = g + gl*((j > 0) + (j < 63)) + (j == 0 ? gin : 0.f);
                float acc = diag*pc - g*pb[A_SZ + row*SP + j];
                if (j > 0)  acc -= gl*pb[base + s - 1];
                if (j < 63) acc -= gl*pb[base + s + 1];
                q[s] = acc; pq += pc*acc;
            }
        } else {
            #pragma unroll
            for (int s = 0; s < PER_T; ++s) {
                int j = jb + s;
                float pc = pb[base + s];
                float g  = G[row*SP + j];
                float diag = g + gl*((row > 0) + (row < 63)) + (row == 63 ? gout : 0.f);
                float acc = diag*pc - g*pb[row*SP + j];
                if (row > 0)  acc -= gl*pb[base + s - SP];
                if (row < 63) acc -= gl*pb[base + s + SP];
                q[s] = acc; pq += pc*acc;
            }
        }
        float pqs = block_reduce(pq, red);
        float alpha = (pqs > 0.f) ? rz/pqs : 0.f;
        #pragma unroll
        for (int s = 0; s < PER_T; ++s) { x[s] += alpha*pb[base + s]; r[s] -= alpha*q[s]; }
        // next iteration's zb writes touch only this thread's own slots; ordering
        // vs. this iteration's readers was enforced by the reduce barriers.
    }

    // ---- K row: K[i0][j] = (1/c) * sum_i G[i][j]*(VA[i][j]-VB[i][j]) ----
    #pragma unroll
    for (int s = 0; s < PER_T; ++s) zb[base + s] = x[s];
    __syncthreads();
    if (t < 64) {
        int j = t; float acc = 0.f;
        #pragma unroll 1
        for (int i = 0; i < 64; ++i)
            acc += G[i*SP + j]*(zb[i*SP + j] - zb[A_SZ + i*SP + j]);
        Kout[i0*64 + j] = acc * 1000.0f;   // fold 1/c
    }
}

// out[b][j] = sum_i x[b][i]*K[i][j] + bias[j]
extern "C" __global__ __launch_bounds__(256)
void apply_k(const float* __restrict__ X, const float* __restrict__ Kmat,
             const float* __restrict__ bias, float* __restrict__ out) {
    int gid = blockIdx.x*256 + threadIdx.x;   // 16384 outputs
    int b = gid >> 6, j = gid & 63;
    float acc = bias[j];
    #pragma unroll
    for (int i = 0; i < 64; ++i) acc += X[b*64 + i]*Kmat[i*64 + j];
    out[gid] = acc;
}

extern "C" void kernel_launch(void* const* d_in, const int* in_sizes, int n_in,
                              void* d_out, int out_size, void* d_ws, size_t ws_size,
                              hipStream_t stream) {
    const float* x    = (const float*)d_in[0];
    const float* w    = (const float*)d_in[1];
    const float* bias = (const float*)d_in[2];
    float* out  = (float*)d_out;
    float* Kmat = (float*)d_ws;                  // 4096 floats

    size_t lds_bytes = (size_t)(7*A_SZ + 8) * sizeof(float);   // ~116.5 KB
    hipFuncSetAttribute((const void*)solve_k,
                        hipFuncAttributeMaxDynamicSharedMemorySize, (int)lds_bytes);

    solve_k<<<64, NT, lds_bytes, stream>>>(w, Kmat);
    apply_k<<<64, 256, 0, stream>>>(x, Kmat, bias, out);
}

// Round 2
// 340.505 us; speedup vs baseline: 1.4807x; 1.4807x over previous
//
#include <hip/hip_runtime.h>

#define SP 65                 // padded stride for [64][j] node arrays
#define A_SZ (64*SP)          // 4160 floats per half
#define SPL 65                // padded stride for U/W line tables (128 lines)
#define NT 512
#define ITERS 48

// LDS float offsets
#define OFF_G    0
#define OFF_U    (OFF_G  + A_SZ)        // 128*SPL = 8320
#define OFF_W    (OFF_U  + 128*SPL)
#define OFF_PB   (OFF_W  + 128*SPL)     // [2][64][SP]
#define OFF_ZB   (OFF_PB + 2*A_SZ)
#define OFF_RED  (OFF_ZB + 2*A_SZ)
#define LDS_FLOATS (OFF_RED + 8)

__device__ __forceinline__ float wave_reduce(float v) {
    #pragma unroll
    for (int off = 32; off > 0; off >>= 1) v += __shfl_down(v, off, 64);
    return v;
}

// One workgroup per unit-input RHS i0. PCG on the SPD crossbar system;
// preconditioner = exact per-line tridiagonal solves applied via the
// semiseparable inverse (T^{-1}_{ij} = U_i W_j, i<=j) with wave-wide scans.
extern "C" __global__ __launch_bounds__(NT)
void solve_k(const float* __restrict__ Wm, float* __restrict__ Kout) {
    extern __shared__ float lds[];
    float* G   = lds + OFF_G;
    float* Ul  = lds + OFF_U;
    float* Wl  = lds + OFF_W;
    float* pb  = lds + OFF_PB;
    float* zb  = lds + OFF_ZB;
    float* red = lds + OFF_RED;

    const int t = threadIdx.x;
    const int wv = t >> 6, lane = t & 63;
    const float gl = 0.5f, gin = 0.5f, gout = 0.5f, c2 = 0.25f;

    // ---- load conductances: G[i][j] = W[j][i]*1e-3 ----
    for (int s = t; s < 4096; s += NT) {
        int i = s >> 6, j = s & 63;
        G[i*SP + j] = Wm[j*64 + i] * 1e-3f;
    }
    __syncthreads();

    // ---- one-time: semiseparable U/W per line (lines 0..63 word i, 64..127 bit j) ----
    if (t < 128) {
        const int line = t; const bool word = line < 64; const int lc = word ? line : line - 64;
        float dprev = 0.f, Ui = 1.0f, prod = 1.0f;
        #pragma unroll 1
        for (int k = 0; k < 64; ++k) {
            float g = word ? G[lc*SP + k] : G[k*SP + lc];
            float b = g + gl*((k>0)+(k<63)) + (word ? (k==0?gin:0.f) : (k==63?gout:0.f));
            Ul[line*SPL + k] = Ui;
            float d = (k == 0) ? b : (b - c2/dprev);
            prod *= gl/d;
            Ui   *= d/gl;
            dprev = d;
        }
        float eprev = 0.f, Wj = prod/gl;
        #pragma unroll 1
        for (int k = 63; k >= 0; --k) {
            float g = word ? G[lc*SP + k] : G[k*SP + lc];
            float b = g + gl*((k>0)+(k<63)) + (word ? (k==0?gin:0.f) : (k==63?gout:0.f));
            if (k == 63) { Wl[line*SPL + 63] = Wj; eprev = b; }
            else { Wj *= eprev/gl; Wl[line*SPL + k] = Wj; eprev = b - c2/eprev; }
        }
    }
    __syncthreads();

    // ---- preload scan coefficients into registers (wave wv: word lines wv*8+li, bit lines wv*8+li) ----
    float su[16], swt[16];
    #pragma unroll
    for (int li = 0; li < 8; ++li) {
        int Lw = wv*8 + li;
        su[li]     = Ul[Lw*SPL + lane];        swt[li]     = Wl[Lw*SPL + lane];
        int Lb = 64 + wv*8 + li;
        su[8 + li] = Ul[Lb*SPL + lane];        swt[8 + li] = Wl[Lb*SPL + lane];
    }

    // ---- node ownership: half0 threads own 16 j-contiguous word nodes of row rc;
    //      half1 threads own 16 i-contiguous bit nodes of column rc ----
    const int half = t >= 256;
    const int tl = t & 255;
    const int rc = tl >> 2;              // row (half0) or col (half1)
    const int sb = (tl & 3) * 16;        // j-base (half0) or i-base (half1)
    const int base_own = half ? (A_SZ + sb*SP + rc) : (rc*SP + sb);
    const int str_own  = half ? SP : 1;

    float gseg[16], dseg[16];
    #pragma unroll
    for (int s = 0; s < 16; ++s) {
        if (!half) {
            int j = sb + s; float g = G[rc*SP + j];
            gseg[s] = g; dseg[s] = g + gl*((j>0)+(j<63)) + (j==0?gin:0.f);
        } else {
            int i = sb + s; float g = G[i*SP + rc];
            gseg[s] = g; dseg[s] = g + gl*((i>0)+(i<63)) + (i==63?gout:0.f);
        }
    }

    float x[16], r[16], p[16];
    #pragma unroll
    for (int s = 0; s < 16; ++s) { x[s] = 0.f; r[s] = 0.f; p[s] = 0.f; }
    if (!half && rc == (int)blockIdx.x && sb == 0) r[0] = gin;   // RHS
    float rz = 0.f;

    #pragma unroll 1
    for (int it = 0; it < ITERS; ++it) {
        // A: r -> zb
        #pragma unroll
        for (int s = 0; s < 16; ++s) zb[base_own + s*str_own] = r[s];
        __syncthreads();

        // B: z = M^{-1} r in place — 16 lines per wave, 2 scans each
        #pragma unroll
        for (int li = 0; li < 16; ++li) {
            int a = (li < 8) ? ((wv*8 + li)*SP + lane)
                             : (A_SZ + lane*SP + (wv*8 + li - 8));
            float rv = zb[a];
            float av = su[li]*rv, bv = swt[li]*rv;
            float pa = av, sbv = bv;
            #pragma unroll
            for (int d2 = 1; d2 < 64; d2 <<= 1) {
                float tv = __shfl_up(pa, d2, 64);
                if (lane >= d2) pa += tv;
            }
            #pragma unroll
            for (int d2 = 1; d2 < 64; d2 <<= 1) {
                float tv = __shfl_down(sbv, d2, 64);
                if (lane + d2 < 64) sbv += tv;
            }
            zb[a] = swt[li]*(pa - av) + su[li]*sbv;
        }
        __syncthreads();

        // C1: rz = r.z ; p = z + beta p ; mirror p -> pb
        float zv[16]; float loc = 0.f;
        #pragma unroll
        for (int s = 0; s < 16; ++s) { zv[s] = zb[base_own + s*str_own]; loc += r[s]*zv[s]; }
        loc = wave_reduce(loc);
        if (lane == 0) red[wv] = loc;
        __syncthreads();
        float rz_new = red[0]+red[1]+red[2]+red[3]+red[4]+red[5]+red[6]+red[7];
        float beta = (it == 0 || rz <= 0.f) ? 0.f : rz_new/rz;
        #pragma unroll
        for (int s = 0; s < 16; ++s) { p[s] = zv[s] + beta*p[s]; pb[base_own + s*str_own] = p[s]; }
        rz = rz_new;
        __syncthreads();

        // D: q = S p ; pq
        float q[16]; float pq = 0.f;
        if (!half) {
            #pragma unroll
            for (int s = 0; s < 16; ++s) {
                int j = sb + s;
                float acc = dseg[s]*p[s] - gseg[s]*pb[A_SZ + rc*SP + j];
                if (j > 0)  acc -= gl * ((s > 0)  ? p[s-1] : pb[rc*SP + j - 1]);
                if (j < 63) acc -= gl * ((s < 15) ? p[s+1] : pb[rc*SP + j + 1]);
                q[s] = acc; pq += p[s]*acc;
            }
        } else {
            #pragma unroll
            for (int s = 0; s < 16; ++s) {
                int i = sb + s;
                float acc = dseg[s]*p[s] - gseg[s]*pb[i*SP + rc];
                if (i > 0)  acc -= gl * ((s > 0)  ? p[s-1] : pb[A_SZ + (i-1)*SP + rc]);
                if (i < 63) acc -= gl * ((s < 15) ? p[s+1] : pb[A_SZ + (i+1)*SP + rc]);
                q[s] = acc; pq += p[s]*acc;
            }
        }
        pq = wave_reduce(pq);
        if (lane == 0) red[wv] = pq;
        __syncthreads();
        float pqs = red[0]+red[1]+red[2]+red[3]+red[4]+red[5]+red[6]+red[7];
        float alpha = (pqs > 0.f) ? rz/pqs : 0.f;
        #pragma unroll
        for (int s = 0; s < 16; ++s) { x[s] += alpha*p[s]; r[s] -= alpha*q[s]; }
    }

    // ---- K row: K[i0][j] = (1/c) * sum_i G[i][j]*(VA[i][j]-VB[i][j]) ----
    #pragma unroll
    for (int s = 0; s < 16; ++s) zb[base_own + s*str_own] = x[s];
    __syncthreads();
    if (t < 64) {
        float acc = 0.f;
        #pragma unroll 1
        for (int i = 0; i < 64; ++i)
            acc += G[i*SP + t]*(zb[i*SP + t] - zb[A_SZ + i*SP + t]);
        Kout[blockIdx.x*64 + t] = acc * 1000.0f;
    }
}

// out[b][j] = sum_i x[b][i]*K[i][j] + bias[j]
extern "C" __global__ __launch_bounds__(256)
void apply_k(const float* __restrict__ X, const float* __restrict__ Kmat,
             const float* __restrict__ bias, float* __restrict__ out) {
    int gid = blockIdx.x*256 + threadIdx.x;   // 16384 outputs
    int b = gid >> 6, j = gid & 63;
    float acc = bias[j];
    #pragma unroll
    for (int i = 0; i < 64; ++i) acc += X[b*64 + i]*Kmat[i*64 + j];
    out[gid] = acc;
}

extern "C" void kernel_launch(void* const* d_in, const int* in_sizes, int n_in,
                              void* d_out, int out_size, void* d_ws, size_t ws_size,
                              hipStream_t stream) {
    const float* x    = (const float*)d_in[0];
    const float* w    = (const float*)d_in[1];
    const float* bias = (const float*)d_in[2];
    float* out  = (float*)d_out;
    float* Kmat = (float*)d_ws;                  // 4096 floats

    size_t lds_bytes = (size_t)LDS_FLOATS * sizeof(float);   // ~146.3 KB
    hipFuncSetAttribute((const void*)solve_k,
                        hipFuncAttributeMaxDynamicSharedMemorySize, (int)lds_bytes);

    solve_k<<<64, NT, lds_bytes, stream>>>(w, Kmat);
    apply_k<<<64, 256, 0, stream>>>(x, Kmat, bias, out);
}

// Round 3
// 172.481 us; speedup vs baseline: 2.9230x; 1.9742x over previous
//
#include <hip/hip_runtime.h>

#define SP 65                 // padded stride for [64][j] node arrays
#define A_SZ (64*SP)          // 4160 floats per half
#define SPL 65                // padded stride for U/W line tables (128 lines)
#define NT 512
#define ITERS 24

// LDS float offsets
#define OFF_G    0
#define OFF_U    (OFF_G + A_SZ)
#define OFF_W    (OFF_U + 128*SPL)
#define OFF_PB   (OFF_W + 128*SPL)      // [2][64][SP] p mirror (cross terms only)
#define OFF_RED0 (OFF_PB + 2*A_SZ)
#define OFF_RED1 (OFF_RED0 + 8)
#define LDS_FLOATS (OFF_RED1 + 8)       // ~116.6 KB

__device__ __forceinline__ float wave_reduce(float v) {
    #pragma unroll
    for (int off = 32; off > 0; off >>= 1) v += __shfl_down(v, off, 64);
    return v;
}

// Apply one line's tridiagonal inverse via semiseparable form, fully in-register:
// z_k = W_k * prefix_{<k}(U*r) + U_k * suffix_{>=k}(W*r)
__device__ __forceinline__ float tri_apply(float r, float su_, float sw_, int lane) {
    float av = su_ * r, bv = sw_ * r;
    float pa = av, sb = bv;
    #pragma unroll
    for (int d2 = 1; d2 < 64; d2 <<= 1) {
        float tu = __shfl_up(pa, d2, 64);
        if (lane >= d2) pa += tu;
        float td = __shfl_down(sb, d2, 64);
        if (lane + d2 < 64) sb += td;
    }
    return sw_ * (pa - av) + su_ * sb;
}

// One workgroup per unit-input RHS i0. PCG on the SPD crossbar system.
// Ownership = scan layout: thread (wv,lane) owns word nodes (i=wv*8+li, j=lane)
// and bit nodes (i=lane, j=wv*8+li). x,r,z,p,q register-resident; LDS only for
// the word<->bit cross term of the matvec and the two scalar reductions.
extern "C" __global__ __launch_bounds__(NT)
void solve_k(const float* __restrict__ Wm, float* __restrict__ Kout) {
    extern __shared__ float lds[];
    float* G    = lds + OFF_G;
    float* Ul   = lds + OFF_U;
    float* Wl   = lds + OFF_W;
    float* pb   = lds + OFF_PB;
    float* red0 = lds + OFF_RED0;
    float* red1 = lds + OFF_RED1;

    const int t = threadIdx.x;
    const int wv = t >> 6, lane = t & 63;
    const float gl = 0.5f, gin = 0.5f, gout = 0.5f, c2 = 0.25f;

    // ---- load conductances: G[i][j] = W[j][i]*1e-3 ----
    for (int s = t; s < 4096; s += NT) {
        int i = s >> 6, j = s & 63;
        G[i*SP + j] = Wm[j*64 + i] * 1e-3f;
    }
    __syncthreads();

    // ---- one-time: semiseparable U/W per line (0..63 word i, 64..127 bit j) ----
    if (t < 128) {
        const int line = t; const bool word = line < 64; const int lc = word ? line : line - 64;
        float dprev = 0.f, Ui = 1.0f, prod = 1.0f;
        #pragma unroll 1
        for (int k = 0; k < 64; ++k) {
            float g = word ? G[lc*SP + k] : G[k*SP + lc];
            float b = g + gl*((k>0)+(k<63)) + (word ? (k==0?gin:0.f) : (k==63?gout:0.f));
            Ul[line*SPL + k] = Ui;
            float d = (k == 0) ? b : (b - c2/dprev);
            prod *= gl/d;
            Ui   *= d/gl;
            dprev = d;
        }
        float eprev = 0.f, Wj = prod/gl;
        #pragma unroll 1
        for (int k = 63; k >= 0; --k) {
            float g = word ? G[lc*SP + k] : G[k*SP + lc];
            float b = g + gl*((k>0)+(k<63)) + (word ? (k==0?gin:0.f) : (k==63?gout:0.f));
            if (k == 63) { Wl[line*SPL + 63] = Wj; eprev = b; }
            else { Wj *= eprev/gl; Wl[line*SPL + k] = Wj; eprev = b - c2/eprev; }
        }
    }
    __syncthreads();

    // ---- preload per-line coefficients into registers ----
    float su[16], swt[16], gseg[16], dseg[16];
    #pragma unroll
    for (int li = 0; li < 8; ++li) {
        const int L = wv*8 + li;
        su[li]  = Ul[L*SPL + lane];        swt[li]  = Wl[L*SPL + lane];
        float g = G[L*SP + lane];          // word line i=L, node j=lane
        gseg[li] = g;
        dseg[li] = g + gl*((lane>0)+(lane<63)) + (lane==0?gin:0.f);
        su[8+li] = Ul[(64+L)*SPL + lane];  swt[8+li] = Wl[(64+L)*SPL + lane];
        float gb = G[lane*SP + L];         // bit line j=L, node i=lane
        gseg[8+li] = gb;
        dseg[8+li] = gb + gl*((lane>0)+(lane<63)) + (lane==63?gout:0.f);
    }

    float xw[8], xb[8], rw[8], rb[8], pw[8], pv[8];
    #pragma unroll
    for (int s = 0; s < 8; ++s) { xw[s]=xb[s]=rw[s]=rb[s]=pw[s]=pv[s]=0.f; }
    const int i0 = blockIdx.x;
    if (wv == (i0 >> 3) && lane == 0) rw[i0 & 7] = gin;   // RHS at node (i0, j=0)
    float rz = 0.f;

    #pragma unroll 1
    for (int it = 0; it < ITERS; ++it) {
        // ---- z = M^{-1} r : pure-register scans ----
        float zw[8], zb2[8];
        #pragma unroll
        for (int li = 0; li < 8; ++li) zw[li]  = tri_apply(rw[li], su[li],   swt[li],   lane);
        #pragma unroll
        for (int li = 0; li < 8; ++li) zb2[li] = tri_apply(rb[li], su[8+li], swt[8+li], lane);

        // ---- rz = r.z ----
        float loc = 0.f;
        #pragma unroll
        for (int li = 0; li < 8; ++li) loc += rw[li]*zw[li] + rb[li]*zb2[li];
        loc = wave_reduce(loc);
        if (lane == 0) red0[wv] = loc;
        __syncthreads();                                   // B1
        float rz_new = red0[0]+red0[1]+red0[2]+red0[3]+red0[4]+red0[5]+red0[6]+red0[7];
        float beta = (it == 0 || rz <= 0.f) ? 0.f : rz_new/rz;

        // ---- p = z + beta p ; mirror p into LDS for cross terms ----
        #pragma unroll
        for (int li = 0; li < 8; ++li) {
            pw[li] = zw[li]  + beta*pw[li];  pb[(wv*8+li)*SP + lane] = pw[li];
            pv[li] = zb2[li] + beta*pv[li];  pb[A_SZ + lane*SP + (wv*8+li)] = pv[li];
        }
        rz = rz_new;
        __syncthreads();                                   // B2: pb visible

        // ---- q = S p : register neighbors via shfl, cross term via LDS ----
        float qw[8], qb[8]; float pq = 0.f;
        #pragma unroll
        for (int li = 0; li < 8; ++li) {
            float pc = pw[li];
            float lf = __shfl_up(pc, 1, 64), rt = __shfl_down(pc, 1, 64);
            float acc = dseg[li]*pc - gseg[li]*pb[A_SZ + (wv*8+li)*SP + lane];
            if (lane > 0)  acc -= gl*lf;
            if (lane < 63) acc -= gl*rt;
            qw[li] = acc; pq += pc*acc;
        }
        #pragma unroll
        for (int li = 0; li < 8; ++li) {
            float pc = pv[li];
            float up = __shfl_up(pc, 1, 64), dn = __shfl_down(pc, 1, 64);
            float acc = dseg[8+li]*pc - gseg[8+li]*pb[lane*SP + (wv*8+li)];
            if (lane > 0)  acc -= gl*up;
            if (lane < 63) acc -= gl*dn;
            qb[li] = acc; pq += pc*acc;
        }
        pq = wave_reduce(pq);
        if (lane == 0) red1[wv] = pq;
        __syncthreads();                                   // B3
        float pqs = red1[0]+red1[1]+red1[2]+red1[3]+red1[4]+red1[5]+red1[6]+red1[7];
        float alpha = (pqs > 0.f) ? rz/pqs : 0.f;
        #pragma unroll
        for (int li = 0; li < 8; ++li) {
            xw[li] += alpha*pw[li];  rw[li] -= alpha*qw[li];
            xb[li] += alpha*pv[li];  rb[li] -= alpha*qb[li];
        }
    }

    // ---- K row: K[i0][j] = 1000 * sum_i G[i][j]*(VA[i][j]-VB[i][j]) ----
    #pragma unroll
    for (int li = 0; li < 8; ++li) {
        pb[(wv*8+li)*SP + lane] = xw[li];
        pb[A_SZ + lane*SP + (wv*8+li)] = xb[li];
    }
    __syncthreads();
    if (t < 64) {
        float acc = 0.f;
        #pragma unroll 1
        for (int i = 0; i < 64; ++i)
            acc += G[i*SP + t]*(pb[i*SP + t] - pb[A_SZ + i*SP + t]);
        Kout[i0*64 + t] = acc * 1000.0f;
    }
}

// out[b][j] = sum_i x[b][i]*K[i][j] + bias[j]
extern "C" __global__ __launch_bounds__(256)
void apply_k(const float* __restrict__ X, const float* __restrict__ Kmat,
             const float* __restrict__ bias, float* __restrict__ out) {
    int gid = blockIdx.x*256 + threadIdx.x;   // 16384 outputs
    int b = gid >> 6, j = gid & 63;
    float acc = bias[j];
    #pragma unroll
    for (int i = 0; i < 64; ++i) acc += X[b*64 + i]*Kmat[i*64 + j];
    out[gid] = acc;
}

extern "C" void kernel_launch(void* const* d_in, const int* in_sizes, int n_in,
                              void* d_out, int out_size, void* d_ws, size_t ws_size,
                              hipStream_t stream) {
    const float* x    = (const float*)d_in[0];
    const float* w    = (const float*)d_in[1];
    const float* bias = (const float*)d_in[2];
    float* out  = (float*)d_out;
    float* Kmat = (float*)d_ws;                  // 4096 floats

    size_t lds_bytes = (size_t)LDS_FLOATS * sizeof(float);
    hipFuncSetAttribute((const void*)solve_k,
                        hipFuncAttributeMaxDynamicSharedMemorySize, (int)lds_bytes);

    solve_k<<<64, NT, lds_bytes, stream>>>(w, Kmat);
    apply_k<<<64, 256, 0, stream>>>(x, Kmat, bias, out);
}

// Round 4
// 130.446 us; speedup vs baseline: 3.8650x; 1.3222x over previous
//
#include <hip/hip_runtime.h>

#define SP 65                 // padded stride for [64][j] node arrays
#define A_SZ (64*SP)          // 4160 floats per half
#define SPL 65                // padded stride for U/W line tables (128 lines)
#define NT 1024
#define ITERS 16

// LDS float offsets
#define OFF_G    0
#define OFF_U    (OFF_G + A_SZ)
#define OFF_W    (OFF_U + 128*SPL)
#define OFF_ZM   (OFF_W + 128*SPL)      // [2][64][SP] z mirror (cross terms)
#define OFF_RED0 (OFF_ZM + 2*A_SZ)
#define OFF_RED1 (OFF_RED0 + 16)
#define LDS_FLOATS (OFF_RED1 + 16)      // ~116.7 KB

__device__ __forceinline__ float wave_reduce(float v) {
    #pragma unroll
    for (int off = 32; off > 0; off >>= 1) v += __shfl_down(v, off, 64);
    return v;
}

// One line's tridiagonal inverse via semiseparable form, in-register:
// z_k = W_k * prefix_{<k}(U*r) + U_k * suffix_{>=k}(W*r)
__device__ __forceinline__ float tri_apply(float r, float su_, float sw_, int lane) {
    float av = su_ * r, bv = sw_ * r;
    float pa = av, sb = bv;
    #pragma unroll
    for (int d2 = 1; d2 < 64; d2 <<= 1) {
        float tu = __shfl_up(pa, d2, 64);
        if (lane >= d2) pa += tu;
        float td = __shfl_down(sb, d2, 64);
        if (lane + d2 < 64) sb += td;
    }
    return sw_ * (pa - av) + su_ * sb;
}

// One workgroup per unit-input RHS i0. Chronopoulos-Gear PCG (single reduction
// per iteration). Wave wv owns word lines i=wv*4+li (node j=lane) and bit
// lines j=wv*4+li (node i=lane). All state register-resident; LDS for the
// word<->bit cross term and the merged scalar reduction. 2 barriers/iter.
extern "C" __global__ __launch_bounds__(NT)
void solve_k(const float* __restrict__ Wm, float* __restrict__ Kout) {
    extern __shared__ float lds[];
    float* G    = lds + OFF_G;
    float* Ul   = lds + OFF_U;
    float* Wl   = lds + OFF_W;
    float* zm   = lds + OFF_ZM;
    float* red0 = lds + OFF_RED0;
    float* red1 = lds + OFF_RED1;

    const int t = threadIdx.x;
    const int wv = t >> 6, lane = t & 63;
    const float gl = 0.5f, gin = 0.5f, gout = 0.5f, c2 = 0.25f;

    // ---- load conductances: G[i][j] = W[j][i]*1e-3 ----
    for (int s = t; s < 4096; s += NT) {
        int i = s >> 6, j = s & 63;
        G[i*SP + j] = Wm[j*64 + i] * 1e-3f;
    }
    __syncthreads();

    // ---- one-time: semiseparable U/W per line (0..63 word i, 64..127 bit j) ----
    if (t < 128) {
        const int line = t; const bool word = line < 64; const int lc = word ? line : line - 64;
        float dprev = 0.f, Ui = 1.0f, prod = 1.0f;
        #pragma unroll 1
        for (int k = 0; k < 64; ++k) {
            float g = word ? G[lc*SP + k] : G[k*SP + lc];
            float b = g + gl*((k>0)+(k<63)) + (word ? (k==0?gin:0.f) : (k==63?gout:0.f));
            Ul[line*SPL + k] = Ui;
            float d = (k == 0) ? b : (b - c2/dprev);
            prod *= gl/d;
            Ui   *= d/gl;
            dprev = d;
        }
        float eprev = 0.f, Wj = prod/gl;
        #pragma unroll 1
        for (int k = 63; k >= 0; --k) {
            float g = word ? G[lc*SP + k] : G[k*SP + lc];
            float b = g + gl*((k>0)+(k<63)) + (word ? (k==0?gin:0.f) : (k==63?gout:0.f));
            if (k == 63) { Wl[line*SPL + 63] = Wj; eprev = b; }
            else { Wj *= eprev/gl; Wl[line*SPL + k] = Wj; eprev = b - c2/eprev; }
        }
    }
    __syncthreads();

    // ---- preload per-line coefficients (li 0..3 word L=wv*4+li, 4..7 bit) ----
    float su[8], swt[8], gsg[8];
    #pragma unroll
    for (int li = 0; li < 4; ++li) {
        const int L = wv*4 + li;
        su[li]   = Ul[L*SPL + lane];       swt[li]   = Wl[L*SPL + lane];
        gsg[li]  = G[L*SP + lane];                       // word line i=L, j=lane
        su[4+li] = Ul[(64+L)*SPL + lane];  swt[4+li] = Wl[(64+L)*SPL + lane];
        gsg[4+li] = G[lane*SP + L];                      // bit line j=L, i=lane
    }

    float x[8], r[8], p[8], q[8];
    #pragma unroll
    for (int s = 0; s < 8; ++s) { x[s]=r[s]=p[s]=q[s]=0.f; }
    const int i0 = blockIdx.x;
    if (wv == (i0 >> 2) && lane == 0) r[i0 & 3] = gin;   // RHS at node (i0, j=0)
    float mu_old = 1.f, al_old = 1.f;

    #pragma unroll 1
    for (int it = 0; it < ITERS; ++it) {
        // ---- z = M^{-1} r : pure-register scans ----
        float z[8];
        #pragma unroll
        for (int li = 0; li < 8; ++li) z[li] = tri_apply(r[li], su[li], swt[li], lane);

        // ---- mirror z for cross terms ----
        #pragma unroll
        for (int li = 0; li < 4; ++li) {
            const int L = wv*4 + li;
            zm[L*SP + lane] = z[li];
            zm[A_SZ + lane*SP + L] = z[4+li];
        }
        __syncthreads();                                  // B1

        // ---- w = S z ; mu = r.z ; dl = z.w ----
        float w[8]; float mu = 0.f, dl = 0.f;
        #pragma unroll
        for (int li = 0; li < 4; ++li) {
            const int L = wv*4 + li;
            float pc = z[li];
            float lf = __shfl_up(pc, 1, 64), rt = __shfl_down(pc, 1, 64);
            float diag = gsg[li] + gl*((lane>0)+(lane<63)) + (lane==0?gin:0.f);
            float acc = diag*pc - gsg[li]*zm[A_SZ + L*SP + lane];
            if (lane > 0)  acc -= gl*lf;
            if (lane < 63) acc -= gl*rt;
            w[li] = acc;
        }
        #pragma unroll
        for (int li = 0; li < 4; ++li) {
            const int L = wv*4 + li;
            float pc = z[4+li];
            float up = __shfl_up(pc, 1, 64), dn = __shfl_down(pc, 1, 64);
            float diag = gsg[4+li] + gl*((lane>0)+(lane<63)) + (lane==63?gout:0.f);
            float acc = diag*pc - gsg[4+li]*zm[lane*SP + L];
            if (lane > 0)  acc -= gl*up;
            if (lane < 63) acc -= gl*dn;
            w[4+li] = acc;
        }
        #pragma unroll
        for (int li = 0; li < 8; ++li) { mu += r[li]*z[li]; dl += z[li]*w[li]; }
        mu = wave_reduce(mu); dl = wave_reduce(dl);
        if (lane == 0) { red0[wv] = mu; red1[wv] = dl; }
        __syncthreads();                                  // B2
        float mus = 0.f, dls = 0.f;
        #pragma unroll
        for (int k = 0; k < 16; ++k) { mus += red0[k]; dls += red1[k]; }

        float beta  = (it == 0) ? 0.f : mus/mu_old;
        float denom = (it == 0) ? dls : (dls - mus*beta/al_old);
        float alpha = (denom != 0.f) ? mus/denom : 0.f;
        #pragma unroll
        for (int li = 0; li < 8; ++li) {
            p[li] = z[li] + beta*p[li];
            q[li] = w[li] + beta*q[li];
            x[li] += alpha*p[li];
            r[li] -= alpha*q[li];
        }
        mu_old = mus; al_old = alpha;
    }

    // ---- K row: K[i0][j] = 1000 * sum_i G[i][j]*(VA[i][j]-VB[i][j]) ----
    #pragma unroll
    for (int li = 0; li < 4; ++li) {
        const int L = wv*4 + li;
        zm[L*SP + lane] = x[li];
        zm[A_SZ + lane*SP + L] = x[4+li];
    }
    __syncthreads();
    float* part = lds + OFF_U;            // reuse Ul region as scratch
    if (t < 256) {
        const int j = t & 63, seg = t >> 6;
        float acc = 0.f;
        #pragma unroll
        for (int i = seg*16; i < seg*16 + 16; ++i)
            acc += G[i*SP + j]*(zm[i*SP + j] - zm[A_SZ + i*SP + j]);
        part[seg*64 + j] = acc;
    }
    __syncthreads();
    if (t < 64)
        Kout[i0*64 + t] = 1000.0f*(part[t] + part[64+t] + part[128+t] + part[192+t]);
}

// out[b][j] = sum_i x[b][i]*K[i][j] + bias[j]
extern "C" __global__ __launch_bounds__(256)
void apply_k(const float* __restrict__ X, const float* __restrict__ Kmat,
             const float* __restrict__ bias, float* __restrict__ out) {
    int gid = blockIdx.x*256 + threadIdx.x;   // 16384 outputs
    int b = gid >> 6, j = gid & 63;
    float acc = bias[j];
    #pragma unroll
    for (int i = 0; i < 64; ++i) acc += X[b*64 + i]*Kmat[i*64 + j];
    out[gid] = acc;
}

extern "C" void kernel_launch(void* const* d_in, const int* in_sizes, int n_in,
                              void* d_out, int out_size, void* d_ws, size_t ws_size,
                              hipStream_t stream) {
    const float* x    = (const float*)d_in[0];
    const float* w    = (const float*)d_in[1];
    const float* bias = (const float*)d_in[2];
    float* out  = (float*)d_out;
    float* Kmat = (float*)d_ws;                  // 4096 floats

    size_t lds_bytes = (size_t)LDS_FLOATS * sizeof(float);
    hipFuncSetAttribute((const void*)solve_k,
                        hipFuncAttributeMaxDynamicSharedMemorySize, (int)lds_bytes);

    solve_k<<<64, NT, lds_bytes, stream>>>(w, Kmat);
    apply_k<<<64, 256, 0, stream>>>(x, Kmat, bias, out);
}

// Round 5
// 57.605 us; speedup vs baseline: 8.7521x; 2.2645x over previous
//
#include <hip/hip_runtime.h>

#define SP 65                 // padded stride for [64][j] node arrays
#define A_SZ (64*SP)          // 4160 floats per half
#define SPL 65                // padded stride for U/W line tables (128 lines)
#define NT 1024
#define SWEEPS 6

// LDS float offsets
#define OFF_G    0
#define OFF_U    (OFF_G + A_SZ)
#define OFF_W    (OFF_U + 128*SPL)
#define OFF_ZM   (OFF_W + 128*SPL)      // [2][64][SP] V_A / V_B mirrors
#define LDS_FLOATS (OFF_ZM + 2*A_SZ)    // ~116.5 KB

// One line's tridiagonal inverse via semiseparable form, in-register:
// z_k = W_k * prefix_{<k}(U*r) + U_k * suffix_{>=k}(W*r)
__device__ __forceinline__ float tri_apply(float r, float su_, float sw_, int lane) {
    float av = su_ * r, bv = sw_ * r;
    float pa = av, sb = bv;
    #pragma unroll
    for (int d2 = 1; d2 < 64; d2 <<= 1) {
        float tu = __shfl_up(pa, d2, 64);
        if (lane >= d2) pa += tu;
        float td = __shfl_down(sb, d2, 64);
        if (lane + d2 < 64) sb += td;
    }
    return sw_ * (pa - av) + su_ * sb;
}

// One workgroup per unit-input RHS i0. Block Gauss-Seidel on the crossbar
// system: V_A = T_r^{-1}(b + Dg V_B), V_B = T_c^{-1}(Dg V_A). Coupling
// sigma^2 ~ 0.09/sweep (device g ~1e-3 S vs line 0.5 S) -> 6 sweeps << fp32.
// Wave wv owns word lines i=wv*4+li (node j=lane) and bit lines j=wv*4+li
// (node i=lane). No reductions; 2 barriers/sweep. Output via column current
// conservation: K[i0][j] = 1000 * gout * V_B[63][j].
extern "C" __global__ __launch_bounds__(NT)
void solve_k(const float* __restrict__ Wm, float* __restrict__ Kout) {
    extern __shared__ float lds[];
    float* G  = lds + OFF_G;
    float* Ul = lds + OFF_U;
    float* Wl = lds + OFF_W;
    float* zm = lds + OFF_ZM;

    const int t = threadIdx.x;
    const int wv = t >> 6, lane = t & 63;
    const float gl = 0.5f, gin = 0.5f, gout = 0.5f, c2 = 0.25f;

    // ---- load conductances: G[i][j] = W[j][i]*1e-3 ----
    for (int s = t; s < 4096; s += NT) {
        int i = s >> 6, j = s & 63;
        G[i*SP + j] = Wm[j*64 + i] * 1e-3f;
    }
    __syncthreads();

    // ---- one-time: semiseparable U/W per line (0..63 word i, 64..127 bit j);
    //      concurrently zero the V_B mirror for sweep 0 ----
    if (t < 128) {
        const int line = t; const bool word = line < 64; const int lc = word ? line : line - 64;
        float dprev = 0.f, Ui = 1.0f, prod = 1.0f;
        #pragma unroll 1
        for (int k = 0; k < 64; ++k) {
            float g = word ? G[lc*SP + k] : G[k*SP + lc];
            float b = g + gl*((k>0)+(k<63)) + (word ? (k==0?gin:0.f) : (k==63?gout:0.f));
            Ul[line*SPL + k] = Ui;
            float d = (k == 0) ? b : (b - c2/dprev);
            prod *= gl/d;
            Ui   *= d/gl;
            dprev = d;
        }
        float eprev = 0.f, Wj = prod/gl;
        #pragma unroll 1
        for (int k = 63; k >= 0; --k) {
            float g = word ? G[lc*SP + k] : G[k*SP + lc];
            float b = g + gl*((k>0)+(k<63)) + (word ? (k==0?gin:0.f) : (k==63?gout:0.f));
            if (k == 63) { Wl[line*SPL + 63] = Wj; eprev = b; }
            else { Wj *= eprev/gl; Wl[line*SPL + k] = Wj; eprev = b - c2/eprev; }
        }
    }
    for (int s = t; s < A_SZ; s += NT) zm[A_SZ + s] = 0.f;   // V_B mirror = 0
    __syncthreads();

    // ---- preload per-line coefficients (li 0..3 word L=wv*4+li, 4..7 bit) ----
    float su[8], swt[8], gsg[8];
    #pragma unroll
    for (int li = 0; li < 4; ++li) {
        const int L = wv*4 + li;
        su[li]   = Ul[L*SPL + lane];       swt[li]   = Wl[L*SPL + lane];
        gsg[li]  = G[L*SP + lane];                       // word line i=L, j=lane
        su[4+li] = Ul[(64+L)*SPL + lane];  swt[4+li] = Wl[(64+L)*SPL + lane];
        gsg[4+li] = G[lane*SP + L];                      // bit line j=L, i=lane
    }

    const int i0 = blockIdx.x;

    #pragma unroll 1
    for (int sw = 0; sw < SWEEPS; ++sw) {
        // ---- word half: V_A = T_r^{-1}(b + Dg V_B) ----
        #pragma unroll
        for (int li = 0; li < 4; ++li) {
            const int L = wv*4 + li;
            float rhs = gsg[li] * zm[A_SZ + L*SP + lane];
            if (L == i0 && lane == 0) rhs += gin;
            float va = tri_apply(rhs, su[li], swt[li], lane);
            zm[L*SP + lane] = va;
        }
        __syncthreads();

        // ---- bit half: V_B = T_c^{-1}(Dg V_A) ----
        #pragma unroll
        for (int li = 0; li < 4; ++li) {
            const int L = wv*4 + li;
            float rhs = gsg[4+li] * zm[lane*SP + L];
            float vb = tri_apply(rhs, su[4+li], swt[4+li], lane);
            if (sw < SWEEPS-1) {
                zm[A_SZ + lane*SP + L] = vb;
            } else if (lane == 63) {
                // K[i0][j] = 1000 * sum_i G_ij (VA-VB)_ij == 1000*gout*VB[63][j]
                Kout[i0*64 + L] = 1000.0f * gout * vb;
            }
        }
        if (sw < SWEEPS-1) __syncthreads();
    }
}

// out[b][j] = sum_i x[b][i]*K[i][j] + bias[j]
extern "C" __global__ __launch_bounds__(256)
void apply_k(const float* __restrict__ X, const float* __restrict__ Kmat,
             const float* __restrict__ bias, float* __restrict__ out) {
    int gid = blockIdx.x*256 + threadIdx.x;   // 16384 outputs
    int b = gid >> 6, j = gid & 63;
    float acc = bias[j];
    #pragma unroll
    for (int i = 0; i < 64; ++i) acc += X[b*64 + i]*Kmat[i*64 + j];
    out[gid] = acc;
}

extern "C" void kernel_launch(void* const* d_in, const int* in_sizes, int n_in,
                              void* d_out, int out_size, void* d_ws, size_t ws_size,
                              hipStream_t stream) {
    const float* x    = (const float*)d_in[0];
    const float* w    = (const float*)d_in[1];
    const float* bias = (const float*)d_in[2];
    float* out  = (float*)d_out;
    float* Kmat = (float*)d_ws;                  // 4096 floats

    size_t lds_bytes = (size_t)LDS_FLOATS * sizeof(float);
    hipFuncSetAttribute((const void*)solve_k,
                        hipFuncAttributeMaxDynamicSharedMemorySize, (int)lds_bytes);

    solve_k<<<64, NT, lds_bytes, stream>>>(w, Kmat);
    apply_k<<<64, 256, 0, stream>>>(x, Kmat, bias, out);
}

// Round 6
// 25.794 us; speedup vs baseline: 19.5457x; 2.2333x over previous
//
#include <hip/hip_runtime.h>

#define SP 65                 // padded stride for [64][j] node arrays
#define A_SZ (64*SP)          // 4160 floats per half
#define SPL 65                // padded stride for U/W line tables (128 lines)
#define NT 1024
#define SWEEPS 5

// LDS float offsets
#define OFF_G    0
#define OFF_U    (OFF_G + A_SZ)
#define OFF_W    (OFF_U + 128*SPL)
#define OFF_ZM   (OFF_W + 128*SPL)      // [2][64][SP] V_A / V_B mirrors
#define OFF_PR   (OFF_ZM + 2*A_SZ)      // [128] per-line prod for W scaling
#define LDS_FLOATS (OFF_PR + 128)       // ~117 KB

// v_mov_dpp with old=0, bound_ctrl -> OOB lanes read 0
template<int CTRL>
__device__ __forceinline__ float dpp0(float v) {
    return __builtin_bit_cast(float,
        __builtin_amdgcn_update_dpp(0, __builtin_bit_cast(int, v), CTRL, 0xF, 0xF, true));
}
__device__ __forceinline__ float rdlane(float v, int l) {
    return __builtin_bit_cast(float, __builtin_amdgcn_readlane(__builtin_bit_cast(int, v), l));
}

struct ScanMasks { float p1, p2, p3, s1, s2, s3; };   // 0/1 per-lane row masks

// One line's tridiagonal inverse via semiseparable form, register/DPP only:
// z_k = W_k * prefix_{<k}(U*r) + U_k * suffix_{>=k}(W*r)
// Prefix: 4x row_shr DPP adds (in-row) + 3 readlane row-total fixups.
// Suffix: 4x row_shl DPP adds + 3 readlane fixups (true scan; NOT total-prefix,
// which would cancel catastrophically given U/W's huge dynamic range).
__device__ __forceinline__ float tri_apply(float r, float su_, float sw_, const ScanMasks& m) {
    float av = su_*r, bv = sw_*r;
    float pa = av;
    pa += dpp0<0x111>(pa);   // row_shr:1
    pa += dpp0<0x112>(pa);   // row_shr:2
    pa += dpp0<0x114>(pa);   // row_shr:4
    pa += dpp0<0x118>(pa);   // row_shr:8
    pa = __fmaf_rn(m.p1, rdlane(pa,15),
         __fmaf_rn(m.p2, rdlane(pa,31),
         __fmaf_rn(m.p3, rdlane(pa,47), pa)));
    float sb = bv;
    sb += dpp0<0x101>(sb);   // row_shl:1
    sb += dpp0<0x102>(sb);   // row_shl:2
    sb += dpp0<0x104>(sb);   // row_shl:4
    sb += dpp0<0x108>(sb);   // row_shl:8
    sb = __fmaf_rn(m.s1, rdlane(sb,16),
         __fmaf_rn(m.s2, rdlane(sb,32),
         __fmaf_rn(m.s3, rdlane(sb,48), sb)));
    return sw_*(pa - av) + su_*sb;
}

// One workgroup per unit-input RHS i0. Block Gauss-Seidel:
// V_A = T_r^{-1}(b + Dg V_B), V_B = T_c^{-1}(Dg V_A); sigma^2 ~ 0.09/sweep.
// Wave wv owns word lines i=wv*4+li (node j=lane) and bit lines j=wv*4+li
// (node i=lane). Output: K[i0][j] = 1000*gout*V_B[63][j] (current conservation).
extern "C" __global__ __launch_bounds__(NT)
void solve_k(const float* __restrict__ Wm, float* __restrict__ Kout) {
    extern __shared__ float lds[];
    float* G  = lds + OFF_G;
    float* Ul = lds + OFF_U;
    float* Wl = lds + OFF_W;
    float* zm = lds + OFF_ZM;
    float* pr = lds + OFF_PR;

    const int t = threadIdx.x;
    const int wv = t >> 6, lane = t & 63;
    const float gl = 0.5f, gin = 0.5f, gout = 0.5f, c2 = 0.25f;

    // ---- load conductances: G[i][j] = W[j][i]*1e-3 ----
    for (int s = t; s < 4096; s += NT) {
        int i = s >> 6, j = s & 63;
        G[i*SP + j] = Wm[j*64 + i] * 1e-3f;
    }
    __syncthreads();

    // ---- factorization: forward (t<128) and backward (128<=t<256) CONCURRENT.
    //      rcp-based (approx 1ulp): only perturbs the preconditioner; GS fixed
    //      point shifts ~1e-6 rel. gl=0.5 divides folded into multiplies. ----
    if (t < 128) {                       // forward: d-recurrence -> Ul, prod
        const int line = t; const bool word = line < 64; const int lc = word ? line : line - 64;
        float Ui = 1.0f, prod = 1.0f, rdprev = 0.f;
        for (int k = 0; k < 64; ++k) {
            float g = word ? G[lc*SP + k] : G[k*SP + lc];
            float b = g + gl*((k>0)+(k<63)) + (word ? (k==0?gin:0.f) : (k==63?gout:0.f));
            float d = b - c2*rdprev;
            Ul[line*SPL + k] = Ui;
            float rd = __builtin_amdgcn_rcpf(d);
            Ui   *= d*2.0f;              // *= d/gl
            prod *= 0.5f*rd;             // *= gl/d
            rdprev = rd;
        }
        pr[line] = prod;
    } else if (t < 256) {                // backward: e-recurrence -> W' (unscaled)
        const int line = t - 128; const bool word = line < 64; const int lc = word ? line : line - 64;
        float Wj = 2.0f, eprev = 0.f;    // W'_63 = 1/gl; prod folded in later
        for (int k = 63; k >= 0; --k) {
            float g = word ? G[lc*SP + k] : G[k*SP + lc];
            float b = g + gl*((k>0)+(k<63)) + (word ? (k==0?gin:0.f) : (k==63?gout:0.f));
            if (k == 63) { Wl[line*SPL + 63] = Wj; eprev = b; }
            else {
                Wj *= eprev*2.0f;        // *= e/gl
                Wl[line*SPL + k] = Wj;
                eprev = b - c2*__builtin_amdgcn_rcpf(eprev);
            }
        }
    }
    for (int s = t; s < A_SZ; s += NT) zm[A_SZ + s] = 0.f;   // V_B = 0
    __syncthreads();

    // ---- scale W' by per-line prod (parallel) ----
    for (int s = t; s < 128*64; s += NT) {
        int line = s >> 6, k = s & 63;
        Wl[line*SPL + k] *= pr[line];
    }
    __syncthreads();

    // ---- preload per-line coefficients (li 0..3 word L=wv*4+li, 4..7 bit) ----
    float su[8], swt[8], gsg[8];
    #pragma unroll
    for (int li = 0; li < 4; ++li) {
        const int L = wv*4 + li;
        su[li]   = Ul[L*SPL + lane];       swt[li]   = Wl[L*SPL + lane];
        gsg[li]  = G[L*SP + lane];                       // word line i=L, j=lane
        su[4+li] = Ul[(64+L)*SPL + lane];  swt[4+li] = Wl[(64+L)*SPL + lane];
        gsg[4+li] = G[lane*SP + L];                      // bit line j=L, i=lane
    }

    const int rrow = lane >> 4;
    ScanMasks m;
    m.p1 = rrow >= 1 ? 1.f : 0.f;  m.p2 = rrow >= 2 ? 1.f : 0.f;  m.p3 = rrow >= 3 ? 1.f : 0.f;
    m.s1 = rrow <  1 ? 1.f : 0.f;  m.s2 = rrow <  2 ? 1.f : 0.f;  m.s3 = rrow <  3 ? 1.f : 0.f;

    const int i0 = blockIdx.x;

    #pragma unroll 1
    for (int sw = 0; sw < SWEEPS; ++sw) {
        // ---- word half: V_A = T_r^{-1}(b + Dg V_B) ----
        #pragma unroll
        for (int li = 0; li < 4; ++li) {
            const int L = wv*4 + li;
            float rhs = gsg[li] * zm[A_SZ + L*SP + lane];
            if (L == i0 && lane == 0) rhs += gin;
            zm[L*SP + lane] = tri_apply(rhs, su[li], swt[li], m);
        }
        __syncthreads();

        // ---- bit half: V_B = T_c^{-1}(Dg V_A) ----
        #pragma unroll
        for (int li = 0; li < 4; ++li) {
            const int L = wv*4 + li;
            float rhs = gsg[4+li] * zm[lane*SP + L];
            float vb = tri_apply(rhs, su[4+li], swt[4+li], m);
            if (sw < SWEEPS-1) {
                zm[A_SZ + lane*SP + L] = vb;
            } else if (lane == 63) {
                // K[i0][j] = 1000 * sum_i G_ij (VA-VB)_ij == 1000*gout*VB[63][j]
                Kout[i0*64 + L] = 1000.0f * gout * vb;
            }
        }
        if (sw < SWEEPS-1) __syncthreads();
    }
}

// out[b][j] = sum_i x[b][i]*K[i][j] + bias[j]
extern "C" __global__ __launch_bounds__(256)
void apply_k(const float* __restrict__ X, const float* __restrict__ Kmat,
             const float* __restrict__ bias, float* __restrict__ out) {
    int gid = blockIdx.x*256 + threadIdx.x;   // 16384 outputs
    int b = gid >> 6, j = gid & 63;
    float acc = bias[j];
    #pragma unroll
    for (int i = 0; i < 64; ++i) acc += X[b*64 + i]*Kmat[i*64 + j];
    out[gid] = acc;
}

extern "C" void kernel_launch(void* const* d_in, const int* in_sizes, int n_in,
                              void* d_out, int out_size, void* d_ws, size_t ws_size,
                              hipStream_t stream) {
    const float* x    = (const float*)d_in[0];
    const float* w    = (const float*)d_in[1];
    const float* bias = (const float*)d_in[2];
    float* out  = (float*)d_out;
    float* Kmat = (float*)d_ws;                  // 4096 floats

    size_t lds_bytes = (size_t)LDS_FLOATS * sizeof(float);
    hipFuncSetAttribute((const void*)solve_k,
                        hipFuncAttributeMaxDynamicSharedMemorySize, (int)lds_bytes);

    solve_k<<<64, NT, lds_bytes, stream>>>(w, Kmat);
    apply_k<<<64, 256, 0, stream>>>(x, Kmat, bias, out);
}

// Round 7
// 21.485 us; speedup vs baseline: 23.4665x; 1.2006x over previous
//
#include <hip/hip_runtime.h>

#define SP 65                 // padded stride
#define A_SZ (64*SP)          // 4160 floats
#define SPL 65
#define NT 1024
#define NBIT 4                // bit-phase applications (exact word-0 init + 3 word phases)

// LDS float offsets (solve_k)
#define OFF_G    0
#define OFF_U    (OFF_G + A_SZ)
#define OFF_W    (OFF_U + 128*SPL)
#define OFF_ZM   (OFF_W + 128*SPL)      // [2][64][SP] V_A / V_B mirrors
#define OFF_PR   (OFF_ZM + 2*A_SZ)      // [128] per-line prod
#define LDS_FLOATS (OFF_PR + 128)       // ~117 KB

// v_mov_dpp with old=0, bound_ctrl -> OOB lanes read 0
template<int CTRL>
__device__ __forceinline__ float dpp0(float v) {
    return __builtin_bit_cast(float,
        __builtin_amdgcn_update_dpp(0, __builtin_bit_cast(int, v), CTRL, 0xF, 0xF, true));
}
__device__ __forceinline__ float rdlane(float v, int l) {
    return __builtin_bit_cast(float, __builtin_amdgcn_readlane(__builtin_bit_cast(int, v), l));
}

struct ScanMasks { float p1, p2, p3, s1, s2, s3; };

// One line's tridiagonal inverse via semiseparable form, register/DPP only:
// z_k = W_k * prefix_{<k}(U*r) + U_k * suffix_{>=k}(W*r)
__device__ __forceinline__ float tri_apply(float r, float su_, float sw_, const ScanMasks& m) {
    float av = su_*r, bv = sw_*r;
    float pa = av;
    pa += dpp0<0x111>(pa);   // row_shr:1
    pa += dpp0<0x112>(pa);   // row_shr:2
    pa += dpp0<0x114>(pa);   // row_shr:4
    pa += dpp0<0x118>(pa);   // row_shr:8
    pa = __fmaf_rn(m.p1, rdlane(pa,15),
         __fmaf_rn(m.p2, rdlane(pa,31),
         __fmaf_rn(m.p3, rdlane(pa,47), pa)));
    float sb = bv;
    sb += dpp0<0x101>(sb);   // row_shl:1
    sb += dpp0<0x102>(sb);   // row_shl:2
    sb += dpp0<0x104>(sb);   // row_shl:4
    sb += dpp0<0x108>(sb);   // row_shl:8
    sb = __fmaf_rn(m.s1, rdlane(sb,16),
         __fmaf_rn(m.s2, rdlane(sb,32),
         __fmaf_rn(m.s3, rdlane(sb,48), sb)));
    return sw_*(pa - av) + su_*sb;
}

// One workgroup per unit-input RHS i0. Block Gauss-Seidel with exact first
// word-phase: V_A^(0) = gin * W_j on line i0 (analytic column of T_r^{-1}),
// then NBIT x { V_B = T_c^{-1}(Dg V_A) ; V_A = T_r^{-1}(b + Dg V_B) }.
// Output: K[i0][j] = 1000*gout*V_B[63][j] (column current conservation).
extern "C" __global__ __launch_bounds__(NT)
void solve_k(const float* __restrict__ Wm, float* __restrict__ Kout) {
    extern __shared__ float lds[];
    float* Gt = lds + OFF_G;            // Gt[j][i] = W[j][i]*1e-3  (input order)
    float* Ul = lds + OFF_U;
    float* Wl = lds + OFF_W;
    float* zm = lds + OFF_ZM;
    float* pr = lds + OFF_PR;

    const int t = threadIdx.x;
    const int wv = t >> 6, lane = t & 63;
    const float gl = 0.5f, gin = 0.5f, gout = 0.5f, c2 = 0.25f;

    // ---- stage conductances, coalesced in input order ----
    for (int s = t; s < 4096; s += NT) {
        int j = s >> 6, i = s & 63;
        Gt[j*SP + i] = Wm[s] * 1e-3f;
    }
    __syncthreads();

    // ---- factorization: forward (t<128) and backward (128<=t<256) concurrent.
    //      rcp-based; gl=0.5 divides folded into multiplies. word line i: G[i][k]=Gt[k*SP+i];
    //      bit line j: G[k][j]=Gt[j*SP+k]. ----
    if (t < 128) {                       // forward: d-recurrence -> Ul, prod
        const int line = t; const bool word = line < 64; const int lc = word ? line : line - 64;
        float Ui = 1.0f, prod = 1.0f, rdprev = 0.f;
        for (int k = 0; k < 64; ++k) {
            float g = word ? Gt[k*SP + lc] : Gt[lc*SP + k];
            float b = g + gl*((k>0)+(k<63)) + (word ? (k==0?gin:0.f) : (k==63?gout:0.f));
            float d = b - c2*rdprev;
            Ul[line*SPL + k] = Ui;
            float rd = __builtin_amdgcn_rcpf(d);
            Ui   *= d*2.0f;              // *= d/gl
            prod *= 0.5f*rd;             // *= gl/d
            rdprev = rd;
        }
        pr[line] = prod;
    } else if (t < 256) {                // backward: e-recurrence -> W' (unscaled)
        const int line = t - 128; const bool word = line < 64; const int lc = word ? line : line - 64;
        float Wj = 2.0f, eprev = 0.f;    // W'_63 = 1/gl
        for (int k = 63; k >= 0; --k) {
            float g = word ? Gt[k*SP + lc] : Gt[lc*SP + k];
            float b = g + gl*((k>0)+(k<63)) + (word ? (k==0?gin:0.f) : (k==63?gout:0.f));
            if (k == 63) { Wl[line*SPL + 63] = Wj; eprev = b; }
            else {
                Wj *= eprev*2.0f;        // *= e/gl
                Wl[line*SPL + k] = Wj;
                eprev = b - c2*__builtin_amdgcn_rcpf(eprev);
            }
        }
    }
    __syncthreads();

    // ---- preload per-line coefficients (prod folded into swt here) ----
    float su[8], swt[8], gsg[8];
    #pragma unroll
    for (int li = 0; li < 4; ++li) {
        const int L = wv*4 + li;
        su[li]    = Ul[L*SPL + lane];
        swt[li]   = Wl[L*SPL + lane] * pr[L];
        gsg[li]   = Gt[lane*SP + L];                    // word line i=L, j=lane
        su[4+li]  = Ul[(64+L)*SPL + lane];
        swt[4+li] = Wl[(64+L)*SPL + lane] * pr[64+L];
        gsg[4+li] = Gt[L*SP + lane];                    // bit line j=L, i=lane
    }

    const int i0 = blockIdx.x;

    // ---- exact sweep-0 word phase: V_A = gin * W_j on line i0, else 0 ----
    #pragma unroll
    for (int li = 0; li < 4; ++li) {
        const int L = wv*4 + li;
        zm[L*SP + lane] = (L == i0) ? gin * swt[li] : 0.f;
    }
    __syncthreads();

    const int rrow = lane >> 4;
    ScanMasks m;
    m.p1 = rrow >= 1 ? 1.f : 0.f;  m.p2 = rrow >= 2 ? 1.f : 0.f;  m.p3 = rrow >= 3 ? 1.f : 0.f;
    m.s1 = rrow <  1 ? 1.f : 0.f;  m.s2 = rrow <  2 ? 1.f : 0.f;  m.s3 = rrow <  3 ? 1.f : 0.f;

    #pragma unroll 1
    for (int sw = 0; sw < NBIT; ++sw) {
        // ---- bit phase: V_B = T_c^{-1}(Dg V_A) ----
        #pragma unroll
        for (int li = 0; li < 4; ++li) {
            const int L = wv*4 + li;
            float rhs = gsg[4+li] * zm[lane*SP + L];
            float vb = tri_apply(rhs, su[4+li], swt[4+li], m);
            if (sw < NBIT-1) {
                zm[A_SZ + lane*SP + L] = vb;
            } else if (lane == 63) {
                // K[i0][j] = 1000 * sum_i G_ij (VA-VB)_ij == 1000*gout*VB[63][j]
                Kout[i0*64 + L] = 1000.0f * gout * vb;
            }
        }
        if (sw == NBIT-1) break;
        __syncthreads();

        // ---- word phase: V_A = T_r^{-1}(b + Dg V_B) ----
        #pragma unroll
        for (int li = 0; li < 4; ++li) {
            const int L = wv*4 + li;
            float rhs = gsg[li] * zm[A_SZ + L*SP + lane];
            if (L == i0 && lane == 0) rhs += gin;
            zm[L*SP + lane] = tri_apply(rhs, su[li], swt[li], m);
        }
        __syncthreads();
    }
}

// out[b][j] = sum_i x[b][i]*K[i][j] + bias[j]; K, X-rows, bias staged in LDS.
extern "C" __global__ __launch_bounds__(256)
void apply_k(const float* __restrict__ X, const float* __restrict__ Kmat,
             const float* __restrict__ bias, float* __restrict__ out) {
    __shared__ float Ks[4096];
    __shared__ float Xs[256];
    __shared__ float Bs[64];
    const int t = threadIdx.x;
    const int b0 = blockIdx.x * 4;

    #pragma unroll
    for (int p = 0; p < 4; ++p)
        *(float4*)&Ks[(p*256 + t)*4] = *(const float4*)&Kmat[(p*256 + t)*4];
    Xs[t] = X[b0*64 + t];                       // 4 rows of X
    if (t < 64) Bs[t] = bias[t];
    __syncthreads();

    const int bl = t >> 6, j = t & 63;
    float acc = Bs[j];
    #pragma unroll 8
    for (int i = 0; i < 64; ++i) acc += Xs[bl*64 + i] * Ks[i*64 + j];
    out[(b0 + bl)*64 + j] = acc;
}

extern "C" void kernel_launch(void* const* d_in, const int* in_sizes, int n_in,
                              void* d_out, int out_size, void* d_ws, size_t ws_size,
                              hipStream_t stream) {
    const float* x    = (const float*)d_in[0];
    const float* w    = (const float*)d_in[1];
    const float* bias = (const float*)d_in[2];
    float* out  = (float*)d_out;
    float* Kmat = (float*)d_ws;                  // 4096 floats

    size_t lds_bytes = (size_t)LDS_FLOATS * sizeof(float);
    hipFuncSetAttribute((const void*)solve_k,
                        hipFuncAttributeMaxDynamicSharedMemorySize, (int)lds_bytes);

    solve_k<<<64, NT, lds_bytes, stream>>>(w, Kmat);
    apply_k<<<64, 256, 0, stream>>>(x, Kmat, bias, out);
}

// Round 8
// 19.236 us; speedup vs baseline: 26.2094x; 1.1169x over previous
//
#include <hip/hip_runtime.h>

#define SP 65                 // padded stride
#define A_SZ (64*SP)          // 4160 floats
#define SPL 65
#define NT 1024
#define NBIT 4                // bit-phase count (exact dense word-0 init + 3 word phases)

// LDS float offsets
#define OFF_G    0
#define OFF_U    (OFF_G + A_SZ)
#define OFF_W    (OFF_U + 128*SPL)
#define OFF_ZM   (OFF_W + 128*SPL)      // [2][64][SP] V_A / V_B mirrors
#define OFF_PR   (OFF_ZM + 2*A_SZ)      // [128] per-line prod
#define OFF_X    (OFF_PR + 128)         // [64] this block's x row
#define OFF_B    (OFF_X + 64)           // [64] bias
#define LDS_FLOATS (OFF_B + 64)         // ~117 KB

// v_mov_dpp with old=0, bound_ctrl -> OOB lanes read 0
template<int CTRL>
__device__ __forceinline__ float dpp0(float v) {
    return __builtin_bit_cast(float,
        __builtin_amdgcn_update_dpp(0, __builtin_bit_cast(int, v), CTRL, 0xF, 0xF, true));
}
__device__ __forceinline__ float rdlane(float v, int l) {
    return __builtin_bit_cast(float, __builtin_amdgcn_readlane(__builtin_bit_cast(int, v), l));
}

struct ScanMasks { float p1, p2, p3, s1, s2, s3; };

// One line's tridiagonal inverse via semiseparable form, register/DPP only:
// z_k = W_k * prefix_{<k}(U*r) + U_k * suffix_{>=k}(W*r)
__device__ __forceinline__ float tri_apply(float r, float su_, float sw_, const ScanMasks& m) {
    float av = su_*r, bv = sw_*r;
    float pa = av;
    pa += dpp0<0x111>(pa);   // row_shr:1
    pa += dpp0<0x112>(pa);   // row_shr:2
    pa += dpp0<0x114>(pa);   // row_shr:4
    pa += dpp0<0x118>(pa);   // row_shr:8
    pa = __fmaf_rn(m.p1, rdlane(pa,15),
         __fmaf_rn(m.p2, rdlane(pa,31),
         __fmaf_rn(m.p3, rdlane(pa,47), pa)));
    float sb = bv;
    sb += dpp0<0x101>(sb);   // row_shl:1
    sb += dpp0<0x102>(sb);   // row_shl:2
    sb += dpp0<0x104>(sb);   // row_shl:4
    sb += dpp0<0x108>(sb);   // row_shl:8
    sb = __fmaf_rn(m.s1, rdlane(sb,16),
         __fmaf_rn(m.s2, rdlane(sb,32),
         __fmaf_rn(m.s3, rdlane(sb,48), sb)));
    return sw_*(pa - av) + su_*sb;
}

// One workgroup per BATCH ROW b (256 blocks, 1/CU). By linearity, solving the
// circuit with RHS g_in*x[b] at word-line inputs gives the final output
// directly: out[b][j] = 1000*g_out*V_B[63][j] + bias[j] (column current
// conservation). Block Gauss-Seidel with exact dense first word-phase:
// V_A^(0)[i][j] = g_in*x_i*W_j^(i), then NBIT x {bit phase ; word phase}.
extern "C" __global__ __launch_bounds__(NT)
void fused_solve(const float* __restrict__ X, const float* __restrict__ Wm,
                 const float* __restrict__ bias, float* __restrict__ out) {
    extern __shared__ float lds[];
    float* Gt = lds + OFF_G;            // Gt[j][i] = W[j][i]*1e-3  (input order)
    float* Ul = lds + OFF_U;
    float* Wl = lds + OFF_W;
    float* zm = lds + OFF_ZM;
    float* pr = lds + OFF_PR;
    float* xs = lds + OFF_X;
    float* bs = lds + OFF_B;

    const int t = threadIdx.x;
    const int wv = t >> 6, lane = t & 63;
    const int b = blockIdx.x;
    const float gl = 0.5f, gin = 0.5f, gout = 0.5f, c2 = 0.25f;

    // ---- stage conductances (coalesced), x row, bias ----
    for (int s = t; s < 4096; s += NT) {
        int j = s >> 6, i = s & 63;
        Gt[j*SP + i] = Wm[s] * 1e-3f;
    }
    if (t < 64) xs[t] = X[b*64 + t];
    else if (t < 128) bs[t-64] = bias[t-64];
    __syncthreads();

    // ---- factorization: forward (t<128) and backward (128<=t<256) concurrent.
    //      rcp-based; gl=0.5 divides folded. word line i: G[i][k]=Gt[k*SP+i];
    //      bit line j: G[k][j]=Gt[j*SP+k]. ----
    if (t < 128) {                       // forward: d-recurrence -> Ul, prod
        const int line = t; const bool word = line < 64; const int lc = word ? line : line - 64;
        float Ui = 1.0f, prod = 1.0f, rdprev = 0.f;
        for (int k = 0; k < 64; ++k) {
            float g = word ? Gt[k*SP + lc] : Gt[lc*SP + k];
            float bb = g + gl*((k>0)+(k<63)) + (word ? (k==0?gin:0.f) : (k==63?gout:0.f));
            float d = bb - c2*rdprev;
            Ul[line*SPL + k] = Ui;
            float rd = __builtin_amdgcn_rcpf(d);
            Ui   *= d*2.0f;              // *= d/gl
            prod *= 0.5f*rd;             // *= gl/d
            rdprev = rd;
        }
        pr[line] = prod;
    } else if (t < 256) {                // backward: e-recurrence -> W' (unscaled)
        const int line = t - 128; const bool word = line < 64; const int lc = word ? line : line - 64;
        float Wj = 2.0f, eprev = 0.f;    // W'_63 = 1/gl
        for (int k = 63; k >= 0; --k) {
            float g = word ? Gt[k*SP + lc] : Gt[lc*SP + k];
            float bb = g + gl*((k>0)+(k<63)) + (word ? (k==0?gin:0.f) : (k==63?gout:0.f));
            if (k == 63) { Wl[line*SPL + 63] = Wj; eprev = bb; }
            else {
                Wj *= eprev*2.0f;        // *= e/gl
                Wl[line*SPL + k] = Wj;
                eprev = bb - c2*__builtin_amdgcn_rcpf(eprev);
            }
        }
    }
    __syncthreads();

    // ---- preload per-line coefficients (prod folded into swt) ----
    float su[8], swt[8], gsg[8], xr[4];
    #pragma unroll
    for (int li = 0; li < 4; ++li) {
        const int L = wv*4 + li;
        su[li]    = Ul[L*SPL + lane];
        swt[li]   = Wl[L*SPL + lane] * pr[L];
        gsg[li]   = Gt[lane*SP + L];                    // word line i=L, j=lane
        su[4+li]  = Ul[(64+L)*SPL + lane];
        swt[4+li] = Wl[(64+L)*SPL + lane] * pr[64+L];
        gsg[4+li] = Gt[L*SP + lane];                    // bit line j=L, i=lane
        xr[li]    = gin * xs[L];                        // g_in * x_i for word line i=L
    }

    // ---- exact sweep-0 word phase (dense RHS): V_A[i][j] = g_in*x_i*W_j^(i) ----
    #pragma unroll
    for (int li = 0; li < 4; ++li) {
        const int L = wv*4 + li;
        zm[L*SP + lane] = xr[li] * swt[li];
    }
    __syncthreads();

    const int rrow = lane >> 4;
    ScanMasks m;
    m.p1 = rrow >= 1 ? 1.f : 0.f;  m.p2 = rrow >= 2 ? 1.f : 0.f;  m.p3 = rrow >= 3 ? 1.f : 0.f;
    m.s1 = rrow <  1 ? 1.f : 0.f;  m.s2 = rrow <  2 ? 1.f : 0.f;  m.s3 = rrow <  3 ? 1.f : 0.f;

    #pragma unroll 1
    for (int sw = 0; sw < NBIT; ++sw) {
        // ---- bit phase: V_B = T_c^{-1}(Dg V_A) ----
        #pragma unroll
        for (int li = 0; li < 4; ++li) {
            const int L = wv*4 + li;
            float rhs = gsg[4+li] * zm[lane*SP + L];
            float vb = tri_apply(rhs, su[4+li], swt[4+li], m);
            if (sw < NBIT-1) {
                zm[A_SZ + lane*SP + L] = vb;
            } else if (lane == 63) {
                // out[b][j] = 1000*g_out*V_B[63][j] + bias[j]
                out[b*64 + L] = 1000.0f * gout * vb + bs[L];
            }
        }
        if (sw == NBIT-1) break;
        __syncthreads();

        // ---- word phase: V_A = T_r^{-1}(b + Dg V_B) ----
        #pragma unroll
        for (int li = 0; li < 4; ++li) {
            const int L = wv*4 + li;
            float rhs = gsg[li] * zm[A_SZ + L*SP + lane];
            if (lane == 0) rhs += xr[li];
            zm[L*SP + lane] = tri_apply(rhs, su[li], swt[li], m);
        }
        __syncthreads();
    }
}

extern "C" void kernel_launch(void* const* d_in, const int* in_sizes, int n_in,
                              void* d_out, int out_size, void* d_ws, size_t ws_size,
                              hipStream_t stream) {
    const float* x    = (const float*)d_in[0];
    const float* w    = (const float*)d_in[1];
    const float* bias = (const float*)d_in[2];
    float* out  = (float*)d_out;

    size_t lds_bytes = (size_t)LDS_FLOATS * sizeof(float);
    hipFuncSetAttribute((const void*)fused_solve,
                        hipFuncAttributeMaxDynamicSharedMemorySize, (int)lds_bytes);

    fused_solve<<<256, NT, lds_bytes, stream>>>(x, w, bias, out);
}

// Round 9
// 17.378 us; speedup vs baseline: 29.0121x; 1.1069x over previous
//
#include <hip/hip_runtime.h>

#define SP 65                 // padded stride
#define A_SZ (64*SP)          // 4160 floats
#define SPL 65
#define NT 512                // 8 waves: fewer barrier participants, 8 scan chains/wave ILP
#define OMEGA 1.05f           // block-SOR: uniform |lambda|=0.05/sweep for sigma^2<=0.18

// LDS float offsets
#define OFF_G    0
#define OFF_U    (OFF_G + A_SZ)
#define OFF_W    (OFF_U + 128*SPL)
#define OFF_ZM   (OFF_W + 128*SPL)      // [2][64][SP] V_A / V_B mirrors
#define OFF_PR   (OFF_ZM + 2*A_SZ)      // [128] per-line prod
#define OFF_X    (OFF_PR + 128)         // [64] this block's x row
#define OFF_B    (OFF_X + 64)           // [64] bias
#define LDS_FLOATS (OFF_B + 64)         // ~117 KB

// v_mov_dpp with old=0, bound_ctrl -> OOB lanes read 0
template<int CTRL>
__device__ __forceinline__ float dpp0(float v) {
    return __builtin_bit_cast(float,
        __builtin_amdgcn_update_dpp(0, __builtin_bit_cast(int, v), CTRL, 0xF, 0xF, true));
}
__device__ __forceinline__ float rdlane(float v, int l) {
    return __builtin_bit_cast(float, __builtin_amdgcn_readlane(__builtin_bit_cast(int, v), l));
}

struct ScanMasks { float p1, p2, p3, s1, s2, s3; };

// One line's tridiagonal inverse via semiseparable form, register/DPP only:
// z_k = W_k * prefix_{<k}(U*r) + U_k * suffix_{>=k}(W*r)
__device__ __forceinline__ float tri_apply(float r, float su_, float sw_, const ScanMasks& m) {
    float av = su_*r, bv = sw_*r;
    float pa = av;
    pa += dpp0<0x111>(pa);   // row_shr:1
    pa += dpp0<0x112>(pa);   // row_shr:2
    pa += dpp0<0x114>(pa);   // row_shr:4
    pa += dpp0<0x118>(pa);   // row_shr:8
    pa = __fmaf_rn(m.p1, rdlane(pa,15),
         __fmaf_rn(m.p2, rdlane(pa,31),
         __fmaf_rn(m.p3, rdlane(pa,47), pa)));
    float sb = bv;
    sb += dpp0<0x101>(sb);   // row_shl:1
    sb += dpp0<0x102>(sb);   // row_shl:2
    sb += dpp0<0x104>(sb);   // row_shl:4
    sb += dpp0<0x108>(sb);   // row_shl:8
    sb = __fmaf_rn(m.s1, rdlane(sb,16),
         __fmaf_rn(m.s2, rdlane(sb,32),
         __fmaf_rn(m.s3, rdlane(sb,48), sb)));
    return sw_*(pa - av) + su_*sb;
}

// One workgroup per BATCH ROW b (256 blocks, 1/CU). Block-SOR (omega=1.05) on
// the 2-cyclic splitting, exact dense first word-phase V_A^0 = T_r^{-1} b,
// then bit,word,bit,word,final-bit (2.5 SOR sweeps). Output via column
// current conservation: out[b][j] = 1000*g_out*V_B[63][j] + bias[j]; the
// final bit phase computes only row 63: z_63 = W_63 * prefix_total(U*r).
extern "C" __global__ __launch_bounds__(NT)
void fused_solve(const float* __restrict__ X, const float* __restrict__ Wm,
                 const float* __restrict__ bias, float* __restrict__ out) {
    extern __shared__ float lds[];
    float* Gt = lds + OFF_G;            // Gt[j][i] = W[j][i]*1e-3  (input order)
    float* Ul = lds + OFF_U;
    float* Wl = lds + OFF_W;
    float* zm = lds + OFF_ZM;
    float* pr = lds + OFF_PR;
    float* xs = lds + OFF_X;
    float* bs = lds + OFF_B;

    const int t = threadIdx.x;
    const int wv = t >> 6, lane = t & 63;
    const int b = blockIdx.x;
    const float gl = 0.5f, gin = 0.5f, gout = 0.5f, c2 = 0.25f;

    // ---- stage conductances (coalesced), x row, bias ----
    for (int s = t; s < 4096; s += NT) {
        int j = s >> 6, i = s & 63;
        Gt[j*SP + i] = Wm[s] * 1e-3f;
    }
    if (t < 64) xs[t] = X[b*64 + t];
    else if (t < 128) bs[t-64] = bias[t-64];
    __syncthreads();

    // ---- factorization: forward (t<128) and backward (128<=t<256) concurrent ----
    if (t < 128) {                       // forward: d-recurrence -> Ul, prod
        const int line = t; const bool word = line < 64; const int lc = word ? line : line - 64;
        float Ui = 1.0f, prod = 1.0f, rdprev = 0.f;
        for (int k = 0; k < 64; ++k) {
            float g = word ? Gt[k*SP + lc] : Gt[lc*SP + k];
            float bb = g + gl*((k>0)+(k<63)) + (word ? (k==0?gin:0.f) : (k==63?gout:0.f));
            float d = bb - c2*rdprev;
            Ul[line*SPL + k] = Ui;
            float rd = __builtin_amdgcn_rcpf(d);
            Ui   *= d*2.0f;              // *= d/gl
            prod *= 0.5f*rd;             // *= gl/d
            rdprev = rd;
        }
        pr[line] = prod;
    } else if (t < 256) {                // backward: e-recurrence -> W' (unscaled)
        const int line = t - 128; const bool word = line < 64; const int lc = word ? line : line - 64;
        float Wj = 2.0f, eprev = 0.f;    // W'_63 = 1/gl
        for (int k = 63; k >= 0; --k) {
            float g = word ? Gt[k*SP + lc] : Gt[lc*SP + k];
            float bb = g + gl*((k>0)+(k<63)) + (word ? (k==0?gin:0.f) : (k==63?gout:0.f));
            if (k == 63) { Wl[line*SPL + 63] = Wj; eprev = bb; }
            else {
                Wj *= eprev*2.0f;        // *= e/gl
                Wl[line*SPL + k] = Wj;
                eprev = bb - c2*__builtin_amdgcn_rcpf(eprev);
            }
        }
    }
    __syncthreads();

    // ---- preload per-line coefficients: 8 word + 8 bit lines per wave ----
    float su[16], swt[16], gsg[16], xr[8], va[8], vb[8];
    #pragma unroll
    for (int li = 0; li < 8; ++li) {
        const int L = wv*8 + li;
        su[li]    = Ul[L*SPL + lane];
        swt[li]   = Wl[L*SPL + lane] * pr[L];
        gsg[li]   = Gt[lane*SP + L];                    // word line i=L, j=lane
        su[8+li]  = Ul[(64+L)*SPL + lane];
        swt[8+li] = Wl[(64+L)*SPL + lane] * pr[64+L];
        gsg[8+li] = Gt[L*SP + lane];                    // bit line j=L, i=lane
        xr[li]    = gin * xs[L];
    }

    // ---- exact init: V_A^0[i][j] = g_in*x_i * U_0 W_j = xr*swt ----
    #pragma unroll
    for (int li = 0; li < 8; ++li) {
        const int L = wv*8 + li;
        va[li] = xr[li] * swt[li];
        vb[li] = 0.f;
        zm[L*SP + lane] = va[li];
    }
    __syncthreads();

    const int rrow = lane >> 4;
    ScanMasks m;
    m.p1 = rrow >= 1 ? 1.f : 0.f;  m.p2 = rrow >= 2 ? 1.f : 0.f;  m.p3 = rrow >= 3 ? 1.f : 0.f;
    m.s1 = rrow <  1 ? 1.f : 0.f;  m.s2 = rrow <  2 ? 1.f : 0.f;  m.s3 = rrow <  3 ? 1.f : 0.f;

    // ---- 2 full SOR sweeps (bit, word) ----
    #pragma unroll 1
    for (int sw = 0; sw < 2; ++sw) {
        #pragma unroll
        for (int li = 0; li < 8; ++li) {            // bit phase
            const int L = wv*8 + li;
            float rhs = gsg[8+li] * zm[lane*SP + L];
            float tri = tri_apply(rhs, su[8+li], swt[8+li], m);
            vb[li] = (1.f-OMEGA)*vb[li] + OMEGA*tri;
            zm[A_SZ + lane*SP + L] = vb[li];
        }
        __syncthreads();
        #pragma unroll
        for (int li = 0; li < 8; ++li) {            // word phase
            const int L = wv*8 + li;
            float rhs = gsg[li] * zm[A_SZ + L*SP + lane];
            if (lane == 0) rhs += xr[li];
            float tri = tri_apply(rhs, su[li], swt[li], m);
            va[li] = (1.f-OMEGA)*va[li] + OMEGA*tri;
            zm[L*SP + lane] = va[li];
        }
        __syncthreads();
    }

    // ---- final bit phase: only row 63 needed; z_63 = W_63 * prefix_total(U*r) ----
    #pragma unroll
    for (int li = 0; li < 8; ++li) {
        const int L = wv*8 + li;
        float rhs = gsg[8+li] * zm[lane*SP + L];
        float pa = su[8+li]*rhs;
        pa += dpp0<0x111>(pa);
        pa += dpp0<0x112>(pa);
        pa += dpp0<0x114>(pa);
        pa += dpp0<0x118>(pa);
        pa = __fmaf_rn(m.p1, rdlane(pa,15),
             __fmaf_rn(m.p2, rdlane(pa,31),
             __fmaf_rn(m.p3, rdlane(pa,47), pa)));
        // at lane 63: pa = inclusive prefix total = sum_k U_k r_k
        float tri63 = swt[8+li] * pa;
        float vbn = (1.f-OMEGA)*vb[li] + OMEGA*tri63;
        if (lane == 63)
            out[b*64 + L] = 1000.0f * gout * vbn + bs[L];
    }
}

extern "C" void kernel_launch(void* const* d_in, const int* in_sizes, int n_in,
                              void* d_out, int out_size, void* d_ws, size_t ws_size,
                              hipStream_t stream) {
    const float* x    = (const float*)d_in[0];
    const float* w    = (const float*)d_in[1];
    const float* bias = (const float*)d_in[2];
    float* out  = (float*)d_out;

    size_t lds_bytes = (size_t)LDS_FLOATS * sizeof(float);
    hipFuncSetAttribute((const void*)fused_solve,
                        hipFuncAttributeMaxDynamicSharedMemorySize, (int)lds_bytes);

    fused_solve<<<256, NT, lds_bytes, stream>>>(x, w, bias, out);
}